// Round 3
// baseline (1037.400 us; speedup 1.0000x reference)
//
#include <hip/hip_runtime.h>
#include <hip/hip_bf16.h>

#define B 32
#define N 4096
#define C 768
#define H 12
#define D 64
#define SCALE 0.125f

typedef __attribute__((ext_vector_type(4))) float f4;

// K1: q[b][j] = sum_c x[b,0,c] * Wq[c,j]
__global__ void k_q(const float* __restrict__ x, const float* __restrict__ Wq,
                    float* __restrict__ q){
  int b = blockIdx.x; int tid = threadIdx.x;
  __shared__ float xs[C];
  for (int j = tid; j < C; j += 256) xs[j] = x[(size_t)b*N*C + j];
  __syncthreads();
  float a0=0.f, a1=0.f, a2=0.f;
  for (int c = 0; c < C; ++c){
    float xv = xs[c];
    const float* w = Wq + (size_t)c*C;
    a0 += xv*w[tid];
    a1 += xv*w[tid+256];
    a2 += xv*w[tid+512];
  }
  q[(size_t)b*C + tid]       = a0;
  q[(size_t)b*C + tid + 256] = a1;
  q[(size_t)b*C + tid + 512] = a2;
}

// K2: r[b][h][c] = SCALE * sum_d q[b,h*64+d] * Wkv[c, h*64+d]   (K-projection folded)
__global__ void k_r(const float* __restrict__ q, const float* __restrict__ Wkv,
                    float* __restrict__ r){
  int b = blockIdx.x, h = blockIdx.y, tid = threadIdx.x;
  __shared__ float qs[D];
  if (tid < D) qs[tid] = q[(size_t)b*C + h*D + tid] * SCALE;
  __syncthreads();
  for (int c = tid; c < C; c += 256){
    const float* w = Wkv + (size_t)c*(2*C) + h*D;
    float acc = 0.f;
    #pragma unroll 8
    for (int d = 0; d < D; ++d) acc += qs[d]*w[d];
    r[((size_t)b*H + h)*C + c] = acc;
  }
}

// K3: spad[b][n][h16] = x[b,n,:] . r[b,h,:]   (thread per token; r loads wave-uniform)
__global__ void k_scores(const float* __restrict__ x, const float* __restrict__ r,
                         float* __restrict__ spad){
  int b = blockIdx.x;
  int n = blockIdx.y*256 + threadIdx.x;
  const float* xp = x + ((size_t)b*N + n)*C;
  const float* rp = r + (size_t)b*H*C;
  float acc[H];
  #pragma unroll
  for (int h=0;h<H;h++) acc[h]=0.f;
  for (int c = 0; c < C; c += 4){
    f4 xv = *(const f4*)(xp + c);
    #pragma unroll
    for (int h=0;h<H;h++){
      const float* rr = rp + (size_t)h*C + c;   // uniform across wave -> s_load
      acc[h] += xv[0]*rr[0] + xv[1]*rr[1] + xv[2]*rr[2] + xv[3]*rr[3];
    }
  }
  float* sp = spad + ((size_t)b*N + n)*16;
  #pragma unroll
  for (int h=0;h<H;h++) sp[h] = acc[h];
}

// K4: in-place softmax over n per (b,h). Block per b; thread tid <-> head tid&15,
// tokens n = (tid>>4) + 16*i  => flat index tid + 256*i (fully coalesced).
__global__ void k_softmax(float* __restrict__ spad){
  int b = blockIdx.x, tid = threadIdx.x;
  int g = tid >> 4, h = tid & 15;
  float* base = spad + (size_t)b*N*16;
  float m = -1e30f;
  for (int i = 0; i < 256; ++i) m = fmaxf(m, base[tid + 256*i]);
  __shared__ float red[16][17];
  red[g][h] = m; __syncthreads();
  for (int st = 8; st > 0; st >>= 1){
    if (g < st) red[g][h] = fmaxf(red[g][h], red[g+st][h]);
    __syncthreads();
  }
  m = red[0][h];
  __syncthreads();
  float l = 0.f;
  for (int i = 0; i < 256; ++i) l += __expf(base[tid + 256*i] - m);
  red[g][h] = l; __syncthreads();
  for (int st = 8; st > 0; st >>= 1){
    if (g < st) red[g][h] += red[g+st][h];
    __syncthreads();
  }
  float inv = 1.0f / red[0][h];
  for (int i = 0; i < 256; ++i){
    int idx = tid + 256*i;
    base[idx] = __expf(base[idx] - m) * inv;
  }
}

// K5: xbar2[half][b][h][c-slice] = sum_{n in half} w[b,n,h] * x[b,n,c]
// grid (B, 12 slices of 64 c, 2 n-halves); block 256 = 4 waves, each wave owns 512 n.
// Weight loads are wave-uniform (n per wave) -> scalar loads; x loads coalesced.
__global__ void k_xbar(const float* __restrict__ x, const float* __restrict__ spad,
                       float* __restrict__ xbar2){
  int b = blockIdx.x, slice = blockIdx.y, half = blockIdx.z;
  int tid = threadIdx.x, w = tid >> 6, lane = tid & 63;
  int c = slice*64 + lane;
  const float* xp = x + (size_t)b*N*C + c;
  const float* wp = spad + (size_t)b*N*16;
  float acc[H];
  #pragma unroll
  for (int h=0;h<H;h++) acc[h]=0.f;
  int n0 = half*2048 + w*512;
  for (int n = n0; n < n0+512; ++n){
    float xv = xp[(size_t)n*C];
    const float* ww = wp + (size_t)n*16;   // wave-uniform -> s_load
    #pragma unroll
    for (int h=0;h<H;h++) acc[h] += ww[h]*xv;
  }
  __shared__ float red[4][H][64];
  #pragma unroll
  for (int h=0;h<H;h++) red[w][h][lane] = acc[h];
  __syncthreads();
  for (int o = tid; o < H*64; o += 256){
    int h = o >> 6, c2 = o & 63;
    float s = red[0][h][c2]+red[1][h][c2]+red[2][h][c2]+red[3][h][c2];
    xbar2[(((size_t)half*B + b)*H + h)*C + slice*64 + c2] = s;
  }
}

// K6: cls[b][h*64+d] = sum_c (xbar_half0+xbar_half1)[b,h,c] * Wkv[c][C + h*64 + d]
__global__ void k_cls(const float* __restrict__ xbar2, const float* __restrict__ Wkv,
                      float* __restrict__ cls){
  int b = blockIdx.x, h = blockIdx.y, tid = threadIdx.x;
  int d = tid & 63, part = tid >> 6;
  __shared__ float xs[C];
  for (int cc = tid; cc < C; cc += 256)
    xs[cc] = xbar2[((size_t)b*H + h)*C + cc] + xbar2[(((size_t)B + b)*H + h)*C + cc];
  __syncthreads();
  float acc = 0.f;
  int c0 = part*192;
  #pragma unroll 4
  for (int cc = c0; cc < c0+192; ++cc)
    acc += xs[cc] * Wkv[(size_t)cc*(2*C) + C + h*D + d];
  __shared__ float red[4][D];
  red[part][d] = acc; __syncthreads();
  if (tid < D)
    cls[(size_t)b*C + h*D + tid] = red[0][tid]+red[1][tid]+red[2][tid]+red[3][tid];
}

// K7: out[b][j] = bp[j] + sum_i cls[b][i] * Wp[i][j]   (fp32 out)
__global__ void k_out(const float* __restrict__ cls, const float* __restrict__ Wp,
                      const float* __restrict__ bp, float* __restrict__ out){
  int b = blockIdx.x, jb = blockIdx.y, tid = threadIdx.x;
  int j = jb*256 + tid;
  __shared__ float xs[C];
  for (int i = tid; i < C; i += 256) xs[i] = cls[(size_t)b*C + i];
  __syncthreads();
  float acc = bp[j];
  #pragma unroll 4
  for (int i = 0; i < C; ++i) acc += xs[i]*Wp[(size_t)i*C + j];
  out[(size_t)b*C + j] = acc;
}

extern "C" void kernel_launch(void* const* d_in, const int* in_sizes, int n_in,
                              void* d_out, int out_size, void* d_ws, size_t ws_size,
                              hipStream_t stream){
  const float* x   = (const float*)d_in[0];
  const float* Wq  = (const float*)d_in[1];
  const float* Wkv = (const float*)d_in[2];
  const float* Wp  = (const float*)d_in[3];
  const float* bp  = (const float*)d_in[4];
  float* out = (float*)d_out;
  char* ws = (char*)d_ws;
  float* q     = (float*)(ws + 0);         //   98,304 B
  float* r     = (float*)(ws + 98304);     // 1,179,648 B
  float* spad  = (float*)(ws + 1277952);   // 8,388,608 B  (B x N x 16 fp32)
  float* xbar2 = (float*)(ws + 9666560);   // 2,359,296 B  (2 halves)
  float* cls   = (float*)(ws + 12025856);  //   98,304 B   (total 12,124,160 B)

  k_q      <<<dim3(B),      dim3(256), 0, stream>>>(x, Wq, q);
  k_r      <<<dim3(B,H),    dim3(256), 0, stream>>>(q, Wkv, r);
  k_scores <<<dim3(B,16),   dim3(256), 0, stream>>>(x, r, spad);
  k_softmax<<<dim3(B),      dim3(256), 0, stream>>>(spad);
  k_xbar   <<<dim3(B,12,2), dim3(256), 0, stream>>>(x, spad, xbar2);
  k_cls    <<<dim3(B,H),    dim3(256), 0, stream>>>(xbar2, Wkv, cls);
  k_out    <<<dim3(B,3),    dim3(256), 0, stream>>>(cls, Wp, bp, out);
}